// Round 1
// baseline (4254.663 us; speedup 1.0000x reference)
//
#include <hip/hip_runtime.h>

#define BB 16
#define TY 255
#define ENC 512
#define EMBD 256
#define DEC 512
#define VV 32000
#define LL 256          // TY+1
#define M4 4096         // B*L
#define GG 2048         // 4*DEC

typedef unsigned short u16;
typedef __attribute__((ext_vector_type(8))) short short8;
typedef __attribute__((ext_vector_type(4))) float f32x4;
typedef __attribute__((ext_vector_type(4))) unsigned short u16x4;

__device__ __forceinline__ u16 f2bf(float f) {
  unsigned u = __float_as_uint(f);
  u += 0x7fff + ((u >> 16) & 1);
  return (u16)(u >> 16);
}
__device__ __forceinline__ float bf2f(u16 h) {
  return __uint_as_float((unsigned)h << 16);
}
__device__ __forceinline__ f32x4 mfma16(short8 a, short8 b, f32x4 c) {
  return __builtin_amdgcn_mfma_f32_16x16x32_bf16(a, b, c, 0, 0, 0);
}
__device__ __forceinline__ float sigmoidf_(float x) { return 1.f / (1.f + expf(-x)); }

// ---------------- generic bf16 MFMA GEMM: C = A @ B(^T) (+bias)(+tanh) ----------------
// A: [M,K] bf16 row-major (lda). BT: B=[N,K] (ldb over K). NN: B=[K,N] (ldb over N).
// Tiles: 64x64, BK=64, 256 threads (4 waves 2x2), M,N,K all multiples of 64.
template<bool BT, bool OBF, bool DOTANH, bool BIAS>
__global__ __launch_bounds__(256) void gemm_kernel(
    const u16* __restrict__ A, const u16* __restrict__ Bm, void* __restrict__ Cv,
    const float* __restrict__ bias,
    int K, int lda, int ldb, int ldc,
    long a_bs, long b_bs, long c_bs)
{
  __shared__ u16 As[64][72];
  __shared__ u16 Bs[64][72];
  const int tid = threadIdx.x;
  const long m0 = (long)blockIdx.y * 64, n0 = (long)blockIdx.x * 64;
  const int z = blockIdx.z;
  const u16* Ab = A + (long)z * a_bs;
  const u16* Bb = Bm + (long)z * b_bs;
  const int lane = tid & 63, w = tid >> 6;
  const int wm = w >> 1, wn = w & 1;
  f32x4 acc[2][2] = {};
  for (int k0 = 0; k0 < K; k0 += 64) {
#pragma unroll
    for (int i = 0; i < 2; i++) {
      int c = tid + 256 * i;
      int r = c >> 3, kk = (c & 7) << 3;
      *(short8*)&As[r][kk] = *(const short8*)&Ab[(m0 + r) * (long)lda + k0 + kk];
    }
    if (BT) {
#pragma unroll
      for (int i = 0; i < 2; i++) {
        int c = tid + 256 * i;
        int r = c >> 3, kk = (c & 7) << 3;
        *(short8*)&Bs[r][kk] = *(const short8*)&Bb[(n0 + r) * (long)ldb + k0 + kk];
      }
    } else {
#pragma unroll
      for (int i = 0; i < 2; i++) {
        int c = tid + 256 * i;
        int kk = c >> 3, nn = (c & 7) << 3;
        const u16* s = &Bb[(long)(k0 + kk) * ldb + n0 + nn];
#pragma unroll
        for (int j = 0; j < 8; j++) Bs[nn + j][kk] = s[j];
      }
    }
    __syncthreads();
#pragma unroll
    for (int kf = 0; kf < 2; kf++) {
      const int ko = kf * 32 + (lane >> 4) * 8;
      short8 a0 = *(const short8*)&As[wm * 32 + (lane & 15)][ko];
      short8 a1 = *(const short8*)&As[wm * 32 + 16 + (lane & 15)][ko];
      short8 b0 = *(const short8*)&Bs[wn * 32 + (lane & 15)][ko];
      short8 b1 = *(const short8*)&Bs[wn * 32 + 16 + (lane & 15)][ko];
      acc[0][0] = mfma16(a0, b0, acc[0][0]);
      acc[0][1] = mfma16(a0, b1, acc[0][1]);
      acc[1][0] = mfma16(a1, b0, acc[1][0]);
      acc[1][1] = mfma16(a1, b1, acc[1][1]);
    }
    __syncthreads();
  }
#pragma unroll
  for (int m = 0; m < 2; m++)
#pragma unroll
    for (int n = 0; n < 2; n++) {
#pragma unroll
      for (int r = 0; r < 4; r++) {
        long row = m0 + wm * 32 + m * 16 + (lane >> 4) * 4 + r;
        long col = n0 + wn * 32 + n * 16 + (lane & 15);
        float v = acc[m][n][r];
        if (BIAS) v += bias[col];
        if (DOTANH) v = tanhf(v);
        if (OBF) ((u16*)Cv)[(long)z * c_bs + row * ldc + col] = f2bf(v);
        else ((float*)Cv)[(long)z * c_bs + row * ldc + col] = v;
      }
    }
}

// ---------------- persistent LSTM: 32 blocks, flag-barrier per step ----------------
// Gate-interleaved layout: permuted gate col n -> orig row (n&3)*512 + (n>>2).
// Block nb owns hidden units [nb*16, nb*16+16) = permuted cols [nb*64, nb*64+64).
// MODE 0: write h into cat[:, 512:1024] (bf16). MODE 1: write h into h2 (bf16, ld 512).
template<int MODE>
__global__ __launch_bounds__(256) void lstm_kernel(
    const float* __restrict__ xw,   // [4096][2048] permuted, biases folded in
    const u16* __restrict__ Whh,    // [2048][512] permuted rows, bf16
    u16* __restrict__ Hbuf,         // [2][16][512] bf16 ping-pong (pre-zeroed)
    u16* __restrict__ hout,
    int* __restrict__ flag)         // pre-zeroed
{
  const int nb = blockIdx.x;
  const int tid = threadIdx.x;
  const int lane = tid & 63, w = tid >> 6;
  const int ncol0 = nb * 64 + w * 16;
  short8 bfrag[16];
  {
    const u16* wr = Whh + (long)(ncol0 + (lane & 15)) * 512 + ((lane >> 4) * 8);
#pragma unroll
    for (int kf = 0; kf < 16; kf++) bfrag[kf] = *(const short8*)&wr[kf * 32];
  }
  const int b = tid >> 4, jl = tid & 15;
  const int jglob = nb * 16 + jl;
  float c = 0.f;
  __shared__ float gbuf[16][64];
  for (int t = 0; t < LL; t++) {
    float4 xg = *(const float4*)&xw[((long)b * LL + t) * GG + nb * 64 + jl * 4];
    const u16* Hin = Hbuf + (t & 1) * (16 * 512);
    const u16* ar = Hin + (lane & 15) * 512 + ((lane >> 4) * 8);
    f32x4 acc0 = {}, acc1 = {};
#pragma unroll
    for (int kf = 0; kf < 8; kf++) {
      short8 a0 = *(const short8*)&ar[(2 * kf) * 32];
      short8 a1 = *(const short8*)&ar[(2 * kf + 1) * 32];
      acc0 = mfma16(a0, bfrag[2 * kf], acc0);
      acc1 = mfma16(a1, bfrag[2 * kf + 1], acc1);
    }
    f32x4 acc = acc0 + acc1;
#pragma unroll
    for (int r = 0; r < 4; r++)
      gbuf[(lane >> 4) * 4 + r][w * 16 + (lane & 15)] = acc[r];
    __syncthreads();
    float gi = sigmoidf_(gbuf[b][jl * 4 + 0] + xg.x);
    float gf = sigmoidf_(gbuf[b][jl * 4 + 1] + xg.y);
    float gg = tanhf(gbuf[b][jl * 4 + 2] + xg.z);
    float go = sigmoidf_(gbuf[b][jl * 4 + 3] + xg.w);
    c = gf * c + gi * gg;
    float h = go * tanhf(c);
    u16 hb = f2bf(h);
    Hbuf[((t + 1) & 1) * (16 * 512) + b * 512 + jglob] = hb;
    if (MODE == 0) hout[((long)b * LL + t) * 1024 + 512 + jglob] = hb;
    else           hout[((long)b * LL + t) * 512 + jglob] = hb;
    __threadfence();
    __syncthreads();
    if (tid == 0) {
      __hip_atomic_fetch_add(flag, 1, __ATOMIC_RELEASE, __HIP_MEMORY_SCOPE_AGENT);
      const int target = 32 * (t + 1);
      while (__hip_atomic_load(flag, __ATOMIC_ACQUIRE, __HIP_MEMORY_SCOPE_AGENT) < target)
        __builtin_amdgcn_s_sleep(1);
    }
    __syncthreads();
  }
}

// ---------------- small kernels ----------------
__global__ void fc1_kernel(const float* __restrict__ x, const float* __restrict__ wgt,
                           const float* __restrict__ bias, float* __restrict__ feat) {
  __shared__ float xs[ENC];
  int bb = blockIdx.x, j = threadIdx.x;
  for (int k = j; k < ENC; k += 256) xs[k] = x[bb * ENC + k];
  __syncthreads();
  float s = bias[j];
  const float* wr = wgt + (long)j * ENC;
  for (int k = 0; k < ENC; k += 4) {
    float4 wv = *(const float4*)&wr[k];
    s += xs[k] * wv.x + xs[k + 1] * wv.y + xs[k + 2] * wv.z + xs[k + 3] * wv.w;
  }
  feat[bb * EMBD + j] = s;
}

__global__ void bn_embed0_kernel(const float* __restrict__ feat, const float* __restrict__ g,
                                 const float* __restrict__ bb, u16* __restrict__ seq) {
  int j = threadIdx.x;  // 256 features, 1 block
  float mu = 0.f, m2 = 0.f;
  for (int i = 0; i < BB; i++) { float v = feat[i * EMBD + j]; mu += v; m2 += v * v; }
  mu *= (1.f / BB);
  float var = m2 * (1.f / BB) - mu * mu;
  float sc = g[j] * rsqrtf(var + 1e-5f);
  float sh = bb[j];
  for (int i = 0; i < BB; i++) {
    float v = (feat[i * EMBD + j] - mu) * sc + sh;
    seq[((long)i * LL) * EMBD + j] = f2bf(v);
  }
}

__global__ void embed_kernel(const int* __restrict__ y, const float* __restrict__ emb,
                             u16* __restrict__ seq) {
  int t = blockIdx.x, bb = blockIdx.y;
  int tok = y[bb * TY + t];
  int j = threadIdx.x;
  seq[((long)bb * LL + 1 + t) * EMBD + j] = f2bf(emb[(long)tok * EMBD + j]);
}

__global__ __launch_bounds__(256) void softmax_kernel(const float* __restrict__ sc,
                                                      u16* __restrict__ wsm) {
  int row = blockIdx.x;
  int q = row & (LL - 1);
  int k = threadIdx.x;
  __shared__ float red[8];
  float v = (k <= q) ? sc[(long)row * LL + k] : -3.4e38f;
  float m = v;
#pragma unroll
  for (int o = 32; o > 0; o >>= 1) m = fmaxf(m, __shfl_xor(m, o));
  if ((k & 63) == 0) red[k >> 6] = m;
  __syncthreads();
  m = fmaxf(fmaxf(red[0], red[1]), fmaxf(red[2], red[3]));
  float e = (k <= q) ? expf(v - m) : 0.f;
  float s = e;
#pragma unroll
  for (int o = 32; o > 0; o >>= 1) s += __shfl_xor(s, o);
  if ((k & 63) == 0) red[4 + (k >> 6)] = s;
  __syncthreads();
  s = red[4] + red[5] + red[6] + red[7];
  wsm[(long)row * LL + k] = f2bf(e / s);
}

__global__ void conv_bf16_kernel(const float* __restrict__ s, u16* __restrict__ d) {
  long i = ((long)blockIdx.x * 256 + threadIdx.x) * 4;
  float4 v = *(const float4*)&s[i];
  u16x4 o = {f2bf(v.x), f2bf(v.y), f2bf(v.z), f2bf(v.w)};
  *(u16x4*)&d[i] = o;
}

__global__ void conv_lstm_w_kernel(const float* __restrict__ s, u16* __restrict__ d, int ldk) {
  int n = blockIdx.x;  // 0..2047 permuted
  int r = (n & 3) * DEC + (n >> 2);
  for (int k = threadIdx.x; k < ldk; k += 256)
    d[(long)n * ldk + k] = f2bf(s[(long)r * ldk + k]);
}

__global__ void conv_lstm_b_kernel(const float* __restrict__ bih, const float* __restrict__ bhh,
                                   float* __restrict__ d) {
  int n = blockIdx.x * 256 + threadIdx.x;
  int r = (n & 3) * DEC + (n >> 2);
  d[n] = bih[r] + bhh[r];
}

extern "C" void kernel_launch(void* const* d_in, const int* in_sizes, int n_in,
                              void* d_out, int out_size, void* d_ws, size_t ws_size,
                              hipStream_t stream) {
  const float* x      = (const float*)d_in[0];
  const int*   y      = (const int*)d_in[1];
  const float* fc1_w  = (const float*)d_in[2];
  const float* fc1_b  = (const float*)d_in[3];
  const float* bn_g   = (const float*)d_in[4];
  const float* bn_b   = (const float*)d_in[5];
  const float* emb    = (const float*)d_in[6];
  const float* l1_Wih = (const float*)d_in[7];
  const float* l1_Whh = (const float*)d_in[8];
  const float* l1_bih = (const float*)d_in[9];
  const float* l1_bhh = (const float*)d_in[10];
  const float* Wout   = (const float*)d_in[11];
  const float* dc_Wih = (const float*)d_in[12];
  const float* dc_Whh = (const float*)d_in[13];
  const float* dc_bih = (const float*)d_in[14];
  const float* dc_bhh = (const float*)d_in[15];
  const float* fc2_w  = (const float*)d_in[16];
  const float* fc2_b  = (const float*)d_in[17];
  float* out = (float*)d_out;

  char* ws = (char*)d_ws;
  float* xw     = (float*)(ws + 0);          // 4096*2048 f32 (reused for both LSTMs)
  u16*   seqb   = (u16*)(ws + 33554432);     // 4096*256 bf16
  u16*   cat    = (u16*)(ws + 35651584);     // 4096*1024 bf16  [mix | h1]
  float* scores = (float*)(ws + 44040192);   // 16*256*256 f32
  u16*   wsm    = (u16*)(ws + 48234496);     // 16*256*256 bf16
  u16*   attnb  = (u16*)(ws + 50331648);     // 4096*512 bf16
  u16*   h2b    = (u16*)(ws + 54525952);     // 4096*512 bf16
  u16*   wih1   = (u16*)(ws + 58720256);     // 2048*256
  u16*   whh1   = (u16*)(ws + 59768832);     // 2048*512
  u16*   wih2   = (u16*)(ws + 61865984);     // 2048*512
  u16*   whh2   = (u16*)(ws + 63963136);     // 2048*512
  u16*   woutb  = (u16*)(ws + 66060288);     // 512*1024
  u16*   fc2wb  = (u16*)(ws + 67108864);     // 32000*512
  float* b1p    = (float*)(ws + 99876864);   // 2048
  float* b2p    = (float*)(ws + 99885056);   // 2048
  float* feat   = (float*)(ws + 99893248);   // 16*256
  u16*   Hb     = (u16*)(ws + 99909632);     // 2 lstms * 2 pings * 16*512
  int*   flags  = (int*)(ws + 99975168);     // 2 * 256B

  hipMemsetAsync(ws + 99909632, 0, 65536 + 512, stream);

  conv_lstm_w_kernel<<<GG, 256, 0, stream>>>(l1_Wih, wih1, EMBD);
  conv_lstm_w_kernel<<<GG, 256, 0, stream>>>(l1_Whh, whh1, DEC);
  conv_lstm_w_kernel<<<GG, 256, 0, stream>>>(dc_Wih, wih2, DEC);
  conv_lstm_w_kernel<<<GG, 256, 0, stream>>>(dc_Whh, whh2, DEC);
  conv_lstm_b_kernel<<<GG / 256, 256, 0, stream>>>(l1_bih, l1_bhh, b1p);
  conv_lstm_b_kernel<<<GG / 256, 256, 0, stream>>>(dc_bih, dc_bhh, b2p);
  conv_bf16_kernel<<<(DEC * 2 * DEC) / 1024, 256, 0, stream>>>(Wout, woutb);
  conv_bf16_kernel<<<(VV * DEC) / 1024, 256, 0, stream>>>(fc2_w, fc2wb);

  fc1_kernel<<<BB, 256, 0, stream>>>(x, fc1_w, fc1_b, feat);
  bn_embed0_kernel<<<1, 256, 0, stream>>>(feat, bn_g, bn_b, seqb);
  embed_kernel<<<dim3(TY, BB), 256, 0, stream>>>(y, emb, seqb);

  // xw1 = seq @ l1_Wih^T + (bih+bhh)   M=4096 N=2048 K=256
  gemm_kernel<true, false, false, true><<<dim3(GG / 64, M4 / 64, 1), 256, 0, stream>>>(
      seqb, wih1, xw, b1p, EMBD, EMBD, EMBD, GG, 0, 0, 0);
  // LSTM1 -> h1 into cat[:,512:1024]
  lstm_kernel<0><<<32, 256, 0, stream>>>(xw, whh1, Hb, cat, flags);
  // scores[b] = h1 @ h1^T   (per batch)
  gemm_kernel<true, false, false, false><<<dim3(LL / 64, LL / 64, BB), 256, 0, stream>>>(
      cat + 512, cat + 512, scores, nullptr, DEC, 1024, 1024, LL,
      (long)LL * 1024, (long)LL * 1024, (long)LL * LL);
  softmax_kernel<<<M4, 256, 0, stream>>>(scores, wsm);
  // mix[b] = wsm @ h1 (NN) -> cat[:,0:512] bf16
  gemm_kernel<false, true, false, false><<<dim3(DEC / 64, LL / 64, BB), 256, 0, stream>>>(
      wsm, cat + 512, cat, nullptr, LL, LL, 1024, 1024,
      (long)LL * LL, (long)LL * 1024, (long)LL * 1024);
  // attn = tanh(cat @ Wout^T)   M=4096 N=512 K=1024
  gemm_kernel<true, true, true, false><<<dim3(DEC / 64, M4 / 64, 1), 256, 0, stream>>>(
      cat, woutb, attnb, nullptr, 1024, 1024, 1024, DEC, 0, 0, 0);
  // xw2 = attn @ dc_Wih^T + (bih+bhh)   M=4096 N=2048 K=512
  gemm_kernel<true, false, false, true><<<dim3(GG / 64, M4 / 64, 1), 256, 0, stream>>>(
      attnb, wih2, xw, b2p, DEC, DEC, DEC, GG, 0, 0, 0);
  // LSTM2 -> h2
  lstm_kernel<1><<<32, 256, 0, stream>>>(xw, whh2, Hb + 2 * 16 * 512, h2b, flags + 64);
  // out = h2 @ fc2_w^T + fc2_b   M=4096 N=32000 K=512
  gemm_kernel<true, false, false, true><<<dim3(VV / 64, M4 / 64, 1), 256, 0, stream>>>(
      h2b, fc2wb, out, fc2_b, DEC, DEC, DEC, VV, 0, 0, 0);
}

// Round 2
// 3874.960 us; speedup vs baseline: 1.0980x; 1.0980x over previous
//
#include <hip/hip_runtime.h>

#define BB 16
#define TY 255
#define ENC 512
#define EMBD 256
#define DEC 512
#define VV 32000
#define LL 256          // TY+1
#define M4 4096         // B*L
#define GG 2048         // 4*DEC

typedef unsigned short u16;
typedef __attribute__((ext_vector_type(8))) short short8;
typedef __attribute__((ext_vector_type(4))) float f32x4;
typedef __attribute__((ext_vector_type(4))) unsigned short u16x4;

__device__ __forceinline__ u16 f2bf(float f) {
  unsigned u = __float_as_uint(f);
  u += 0x7fff + ((u >> 16) & 1);
  return (u16)(u >> 16);
}
__device__ __forceinline__ float bf2f(u16 h) {
  return __uint_as_float((unsigned)h << 16);
}
__device__ __forceinline__ f32x4 mfma16(short8 a, short8 b, f32x4 c) {
  return __builtin_amdgcn_mfma_f32_16x16x32_bf16(a, b, c, 0, 0, 0);
}
__device__ __forceinline__ float sigmoidf_(float x) { return 1.f / (1.f + expf(-x)); }

// ---------------- generic bf16 MFMA GEMM: C = A @ B(^T) (+bias)(+tanh) ----------------
// A: [M,K] bf16 row-major (lda). BT: B=[N,K] (ldb over K). NN: B=[K,N] (ldb over N).
// Tiles: 64x64, BK=64, 256 threads (4 waves 2x2), M,N,K all multiples of 64.
template<bool BT, bool OBF, bool DOTANH, bool BIAS>
__global__ __launch_bounds__(256) void gemm_kernel(
    const u16* __restrict__ A, const u16* __restrict__ Bm, void* __restrict__ Cv,
    const float* __restrict__ bias,
    int K, int lda, int ldb, int ldc,
    long a_bs, long b_bs, long c_bs)
{
  __shared__ u16 As[64][72];
  __shared__ u16 Bs[64][72];
  const int tid = threadIdx.x;
  const long m0 = (long)blockIdx.y * 64, n0 = (long)blockIdx.x * 64;
  const int z = blockIdx.z;
  const u16* Ab = A + (long)z * a_bs;
  const u16* Bb = Bm + (long)z * b_bs;
  const int lane = tid & 63, w = tid >> 6;
  const int wm = w >> 1, wn = w & 1;
  f32x4 acc[2][2] = {};
  for (int k0 = 0; k0 < K; k0 += 64) {
#pragma unroll
    for (int i = 0; i < 2; i++) {
      int c = tid + 256 * i;
      int r = c >> 3, kk = (c & 7) << 3;
      *(short8*)&As[r][kk] = *(const short8*)&Ab[(m0 + r) * (long)lda + k0 + kk];
    }
    if (BT) {
#pragma unroll
      for (int i = 0; i < 2; i++) {
        int c = tid + 256 * i;
        int r = c >> 3, kk = (c & 7) << 3;
        *(short8*)&Bs[r][kk] = *(const short8*)&Bb[(n0 + r) * (long)ldb + k0 + kk];
      }
    } else {
#pragma unroll
      for (int i = 0; i < 2; i++) {
        int c = tid + 256 * i;
        int kk = c >> 3, nn = (c & 7) << 3;
        const u16* s = &Bb[(long)(k0 + kk) * ldb + n0 + nn];
#pragma unroll
        for (int j = 0; j < 8; j++) Bs[nn + j][kk] = s[j];
      }
    }
    __syncthreads();
#pragma unroll
    for (int kf = 0; kf < 2; kf++) {
      const int ko = kf * 32 + (lane >> 4) * 8;
      short8 a0 = *(const short8*)&As[wm * 32 + (lane & 15)][ko];
      short8 a1 = *(const short8*)&As[wm * 32 + 16 + (lane & 15)][ko];
      short8 b0 = *(const short8*)&Bs[wn * 32 + (lane & 15)][ko];
      short8 b1 = *(const short8*)&Bs[wn * 32 + 16 + (lane & 15)][ko];
      acc[0][0] = mfma16(a0, b0, acc[0][0]);
      acc[0][1] = mfma16(a0, b1, acc[0][1]);
      acc[1][0] = mfma16(a1, b0, acc[1][0]);
      acc[1][1] = mfma16(a1, b1, acc[1][1]);
    }
    __syncthreads();
  }
#pragma unroll
  for (int m = 0; m < 2; m++)
#pragma unroll
    for (int n = 0; n < 2; n++) {
#pragma unroll
      for (int r = 0; r < 4; r++) {
        long row = m0 + wm * 32 + m * 16 + (lane >> 4) * 4 + r;
        long col = n0 + wn * 32 + n * 16 + (lane & 15);
        float v = acc[m][n][r];
        if (BIAS) v += bias[col];
        if (DOTANH) v = tanhf(v);
        if (OBF) ((u16*)Cv)[(long)z * c_bs + row * ldc + col] = f2bf(v);
        else ((float*)Cv)[(long)z * c_bs + row * ldc + col] = v;
      }
    }
}

// ---------------- persistent LSTM: 32 blocks, per-block-flag barrier per step ----------------
// Gate-interleaved layout: permuted gate col n -> orig row (n&3)*512 + (n>>2).
// Block nb owns hidden units [nb*16, nb*16+16) = permuted cols [nb*64, nb*64+64).
// MODE 0: write h into cat[:, 512:1024] (bf16). MODE 1: write h into h2 (bf16, ld 512).
// Barrier: each block store-releases its own flag word (no RMW contention);
// wave 0 lanes 0..31 poll the 32 flags with acquire loads (hang-safe: inv purges
// any stale line so the next poll refetches); all-wave acquire fence before reads.
template<int MODE>
__global__ __launch_bounds__(256) void lstm_kernel(
    const float* __restrict__ xw,   // [4096][2048] permuted, biases folded in
    const u16* __restrict__ Whh,    // [2048][512] permuted rows, bf16
    u16* __restrict__ Hbuf,         // [2][16][512] bf16 ping-pong (pre-zeroed)
    u16* __restrict__ hout,
    int* __restrict__ flag)         // 32 ints, pre-zeroed
{
  const int nb = blockIdx.x;
  const int tid = threadIdx.x;
  const int lane = tid & 63, w = tid >> 6;
  const int ncol0 = nb * 64 + w * 16;
  short8 bfrag[16];
  {
    const u16* wr = Whh + (long)(ncol0 + (lane & 15)) * 512 + ((lane >> 4) * 8);
#pragma unroll
    for (int kf = 0; kf < 16; kf++) bfrag[kf] = *(const short8*)&wr[kf * 32];
  }
  const int b = tid >> 4, jl = tid & 15;
  const int jglob = nb * 16 + jl;
  float c = 0.f;
  __shared__ float gbuf[16][64];
  // prefetch step-0 gate pre-activations (xw is immutable -> safe to hoist)
  float4 xg = *(const float4*)&xw[((long)b * LL + 0) * GG + nb * 64 + jl * 4];
  for (int t = 0; t < LL; t++) {
    const u16* Hin = Hbuf + (t & 1) * (16 * 512);
    const u16* ar = Hin + (lane & 15) * 512 + ((lane >> 4) * 8);
    f32x4 acc0 = {}, acc1 = {};
#pragma unroll
    for (int kf = 0; kf < 8; kf++) {
      short8 a0 = *(const short8*)&ar[(2 * kf) * 32];
      short8 a1 = *(const short8*)&ar[(2 * kf + 1) * 32];
      acc0 = mfma16(a0, bfrag[2 * kf], acc0);
      acc1 = mfma16(a1, bfrag[2 * kf + 1], acc1);
    }
    f32x4 acc = acc0 + acc1;
#pragma unroll
    for (int r = 0; r < 4; r++)
      gbuf[(lane >> 4) * 4 + r][w * 16 + (lane & 15)] = acc[r];
    __syncthreads();
    float gi = sigmoidf_(gbuf[b][jl * 4 + 0] + xg.x);
    float gf = sigmoidf_(gbuf[b][jl * 4 + 1] + xg.y);
    float gg = tanhf(gbuf[b][jl * 4 + 2] + xg.z);
    float go = sigmoidf_(gbuf[b][jl * 4 + 3] + xg.w);
    c = gf * c + gi * gg;
    float h = go * tanhf(c);
    u16 hb = f2bf(h);
    Hbuf[((t + 1) & 1) * (16 * 512) + b * 512 + jglob] = hb;
    if (MODE == 0) hout[((long)b * LL + t) * 1024 + 512 + jglob] = hb;
    else           hout[((long)b * LL + t) * 512 + jglob] = hb;
    // __syncthreads drains every wave's stores (vmcnt(0) before s_barrier);
    // the release below writes back the XCD L2 so readers see h via L3.
    __syncthreads();
    if (tid == 0)
      __hip_atomic_store(&flag[nb], t + 1, __ATOMIC_RELEASE, __HIP_MEMORY_SCOPE_AGENT);
    // prefetch next step's xw slice into registers while waiting
    float4 xg_next = {};
    if (t + 1 < LL)
      xg_next = *(const float4*)&xw[((long)b * LL + (t + 1)) * GG + nb * 64 + jl * 4];
    if (w == 0) {
      const int target = t + 1;
      bool ok;
      do {
        int v = (lane < 32)
                    ? __hip_atomic_load(&flag[lane], __ATOMIC_ACQUIRE, __HIP_MEMORY_SCOPE_AGENT)
                    : target;
        ok = __all(v >= target);
      } while (!ok);
    }
    __syncthreads();
    __builtin_amdgcn_fence(__ATOMIC_ACQUIRE, "agent");
    xg = xg_next;
  }
}

// ---------------- small kernels ----------------
__global__ void fc1_kernel(const float* __restrict__ x, const float* __restrict__ wgt,
                           const float* __restrict__ bias, float* __restrict__ feat) {
  __shared__ float xs[ENC];
  int bb = blockIdx.x, j = threadIdx.x;
  for (int k = j; k < ENC; k += 256) xs[k] = x[bb * ENC + k];
  __syncthreads();
  float s = bias[j];
  const float* wr = wgt + (long)j * ENC;
  for (int k = 0; k < ENC; k += 4) {
    float4 wv = *(const float4*)&wr[k];
    s += xs[k] * wv.x + xs[k + 1] * wv.y + xs[k + 2] * wv.z + xs[k + 3] * wv.w;
  }
  feat[bb * EMBD + j] = s;
}

__global__ void bn_embed0_kernel(const float* __restrict__ feat, const float* __restrict__ g,
                                 const float* __restrict__ bb, u16* __restrict__ seq) {
  int j = threadIdx.x;  // 256 features, 1 block
  float mu = 0.f, m2 = 0.f;
  for (int i = 0; i < BB; i++) { float v = feat[i * EMBD + j]; mu += v; m2 += v * v; }
  mu *= (1.f / BB);
  float var = m2 * (1.f / BB) - mu * mu;
  float sc = g[j] * rsqrtf(var + 1e-5f);
  float sh = bb[j];
  for (int i = 0; i < BB; i++) {
    float v = (feat[i * EMBD + j] - mu) * sc + sh;
    seq[((long)i * LL) * EMBD + j] = f2bf(v);
  }
}

__global__ void embed_kernel(const int* __restrict__ y, const float* __restrict__ emb,
                             u16* __restrict__ seq) {
  int t = blockIdx.x, bb = blockIdx.y;
  int tok = y[bb * TY + t];
  int j = threadIdx.x;
  seq[((long)bb * LL + 1 + t) * EMBD + j] = f2bf(emb[(long)tok * EMBD + j]);
}

__global__ __launch_bounds__(256) void softmax_kernel(const float* __restrict__ sc,
                                                      u16* __restrict__ wsm) {
  int row = blockIdx.x;
  int q = row & (LL - 1);
  int k = threadIdx.x;
  __shared__ float red[8];
  float v = (k <= q) ? sc[(long)row * LL + k] : -3.4e38f;
  float m = v;
#pragma unroll
  for (int o = 32; o > 0; o >>= 1) m = fmaxf(m, __shfl_xor(m, o));
  if ((k & 63) == 0) red[k >> 6] = m;
  __syncthreads();
  m = fmaxf(fmaxf(red[0], red[1]), fmaxf(red[2], red[3]));
  float e = (k <= q) ? expf(v - m) : 0.f;
  float s = e;
#pragma unroll
  for (int o = 32; o > 0; o >>= 1) s += __shfl_xor(s, o);
  if ((k & 63) == 0) red[4 + (k >> 6)] = s;
  __syncthreads();
  s = red[4] + red[5] + red[6] + red[7];
  wsm[(long)row * LL + k] = f2bf(e / s);
}

__global__ void conv_bf16_kernel(const float* __restrict__ s, u16* __restrict__ d) {
  long i = ((long)blockIdx.x * 256 + threadIdx.x) * 4;
  float4 v = *(const float4*)&s[i];
  u16x4 o = {f2bf(v.x), f2bf(v.y), f2bf(v.z), f2bf(v.w)};
  *(u16x4*)&d[i] = o;
}

__global__ void conv_lstm_w_kernel(const float* __restrict__ s, u16* __restrict__ d, int ldk) {
  int n = blockIdx.x;  // 0..2047 permuted
  int r = (n & 3) * DEC + (n >> 2);
  for (int k = threadIdx.x; k < ldk; k += 256)
    d[(long)n * ldk + k] = f2bf(s[(long)r * ldk + k]);
}

__global__ void conv_lstm_b_kernel(const float* __restrict__ bih, const float* __restrict__ bhh,
                                   float* __restrict__ d) {
  int n = blockIdx.x * 256 + threadIdx.x;
  int r = (n & 3) * DEC + (n >> 2);
  d[n] = bih[r] + bhh[r];
}

extern "C" void kernel_launch(void* const* d_in, const int* in_sizes, int n_in,
                              void* d_out, int out_size, void* d_ws, size_t ws_size,
                              hipStream_t stream) {
  const float* x      = (const float*)d_in[0];
  const int*   y      = (const int*)d_in[1];
  const float* fc1_w  = (const float*)d_in[2];
  const float* fc1_b  = (const float*)d_in[3];
  const float* bn_g   = (const float*)d_in[4];
  const float* bn_b   = (const float*)d_in[5];
  const float* emb    = (const float*)d_in[6];
  const float* l1_Wih = (const float*)d_in[7];
  const float* l1_Whh = (const float*)d_in[8];
  const float* l1_bih = (const float*)d_in[9];
  const float* l1_bhh = (const float*)d_in[10];
  const float* Wout   = (const float*)d_in[11];
  const float* dc_Wih = (const float*)d_in[12];
  const float* dc_Whh = (const float*)d_in[13];
  const float* dc_bih = (const float*)d_in[14];
  const float* dc_bhh = (const float*)d_in[15];
  const float* fc2_w  = (const float*)d_in[16];
  const float* fc2_b  = (const float*)d_in[17];
  float* out = (float*)d_out;

  char* ws = (char*)d_ws;
  float* xw     = (float*)(ws + 0);          // 4096*2048 f32 (reused for both LSTMs)
  u16*   seqb   = (u16*)(ws + 33554432);     // 4096*256 bf16
  u16*   cat    = (u16*)(ws + 35651584);     // 4096*1024 bf16  [mix | h1]
  float* scores = (float*)(ws + 44040192);   // 16*256*256 f32
  u16*   wsm    = (u16*)(ws + 48234496);     // 16*256*256 bf16
  u16*   attnb  = (u16*)(ws + 50331648);     // 4096*512 bf16
  u16*   h2b    = (u16*)(ws + 54525952);     // 4096*512 bf16
  u16*   wih1   = (u16*)(ws + 58720256);     // 2048*256
  u16*   whh1   = (u16*)(ws + 59768832);     // 2048*512
  u16*   wih2   = (u16*)(ws + 61865984);     // 2048*512
  u16*   whh2   = (u16*)(ws + 63963136);     // 2048*512
  u16*   woutb  = (u16*)(ws + 66060288);     // 512*1024
  u16*   fc2wb  = (u16*)(ws + 67108864);     // 32000*512
  float* b1p    = (float*)(ws + 99876864);   // 2048
  float* b2p    = (float*)(ws + 99885056);   // 2048
  float* feat   = (float*)(ws + 99893248);   // 16*256
  u16*   Hb     = (u16*)(ws + 99909632);     // 2 lstms * 2 pings * 16*512
  int*   flags  = (int*)(ws + 99975168);     // 2 * 256B

  hipMemsetAsync(ws + 99909632, 0, 65536 + 512, stream);

  conv_lstm_w_kernel<<<GG, 256, 0, stream>>>(l1_Wih, wih1, EMBD);
  conv_lstm_w_kernel<<<GG, 256, 0, stream>>>(l1_Whh, whh1, DEC);
  conv_lstm_w_kernel<<<GG, 256, 0, stream>>>(dc_Wih, wih2, DEC);
  conv_lstm_w_kernel<<<GG, 256, 0, stream>>>(dc_Whh, whh2, DEC);
  conv_lstm_b_kernel<<<GG / 256, 256, 0, stream>>>(l1_bih, l1_bhh, b1p);
  conv_lstm_b_kernel<<<GG / 256, 256, 0, stream>>>(dc_bih, dc_bhh, b2p);
  conv_bf16_kernel<<<(DEC * 2 * DEC) / 1024, 256, 0, stream>>>(Wout, woutb);
  conv_bf16_kernel<<<(VV * DEC) / 1024, 256, 0, stream>>>(fc2_w, fc2wb);

  fc1_kernel<<<BB, 256, 0, stream>>>(x, fc1_w, fc1_b, feat);
  bn_embed0_kernel<<<1, 256, 0, stream>>>(feat, bn_g, bn_b, seqb);
  embed_kernel<<<dim3(TY, BB), 256, 0, stream>>>(y, emb, seqb);

  // xw1 = seq @ l1_Wih^T + (bih+bhh)   M=4096 N=2048 K=256
  gemm_kernel<true, false, false, true><<<dim3(GG / 64, M4 / 64, 1), 256, 0, stream>>>(
      seqb, wih1, xw, b1p, EMBD, EMBD, EMBD, GG, 0, 0, 0);
  // LSTM1 -> h1 into cat[:,512:1024]
  lstm_kernel<0><<<32, 256, 0, stream>>>(xw, whh1, Hb, cat, flags);
  // scores[b] = h1 @ h1^T   (per batch)
  gemm_kernel<true, false, false, false><<<dim3(LL / 64, LL / 64, BB), 256, 0, stream>>>(
      cat + 512, cat + 512, scores, nullptr, DEC, 1024, 1024, LL,
      (long)LL * 1024, (long)LL * 1024, (long)LL * LL);
  softmax_kernel<<<M4, 256, 0, stream>>>(scores, wsm);
  // mix[b] = wsm @ h1 (NN) -> cat[:,0:512] bf16
  gemm_kernel<false, true, false, false><<<dim3(DEC / 64, LL / 64, BB), 256, 0, stream>>>(
      wsm, cat + 512, cat, nullptr, LL, LL, 1024, 1024,
      (long)LL * LL, (long)LL * 1024, (long)LL * 1024);
  // attn = tanh(cat @ Wout^T)   M=4096 N=512 K=1024
  gemm_kernel<true, true, true, false><<<dim3(DEC / 64, M4 / 64, 1), 256, 0, stream>>>(
      cat, woutb, attnb, nullptr, 1024, 1024, 1024, DEC, 0, 0, 0);
  // xw2 = attn @ dc_Wih^T + (bih+bhh)   M=4096 N=2048 K=512
  gemm_kernel<true, false, false, true><<<dim3(GG / 64, M4 / 64, 1), 256, 0, stream>>>(
      attnb, wih2, xw, b2p, DEC, DEC, DEC, GG, 0, 0, 0);
  // LSTM2 -> h2
  lstm_kernel<1><<<32, 256, 0, stream>>>(xw, whh2, Hb + 2 * 16 * 512, h2b, flags + 64);
  // out = h2 @ fc2_w^T + fc2_b   M=4096 N=32000 K=512
  gemm_kernel<true, false, false, true><<<dim3(VV / 64, M4 / 64, 1), 256, 0, stream>>>(
      h2b, fc2wb, out, fc2_b, DEC, DEC, DEC, VV, 0, 0, 0);
}

// Round 3
// 2579.483 us; speedup vs baseline: 1.6494x; 1.5022x over previous
//
#include <hip/hip_runtime.h>

#define BB 16
#define TY 255
#define ENC 512
#define EMBD 256
#define DEC 512
#define VV 32000
#define LL 256          // TY+1
#define M4 4096         // B*L
#define GG 2048         // 4*DEC

typedef unsigned short u16;
typedef __attribute__((ext_vector_type(8))) short short8;
typedef __attribute__((ext_vector_type(4))) float f32x4;
typedef __attribute__((ext_vector_type(4))) unsigned short u16x4;

__device__ __forceinline__ u16 f2bf(float f) {
  unsigned u = __float_as_uint(f);
  u += 0x7fff + ((u >> 16) & 1);
  return (u16)(u >> 16);
}
__device__ __forceinline__ float bf2f(u16 h) {
  return __uint_as_float((unsigned)h << 16);
}
__device__ __forceinline__ f32x4 mfma16(short8 a, short8 b, f32x4 c) {
  return __builtin_amdgcn_mfma_f32_16x16x32_bf16(a, b, c, 0, 0, 0);
}
__device__ __forceinline__ float sigmoidf_(float x) { return 1.f / (1.f + expf(-x)); }

// ---- system-scope (L1+L2 bypass, coherent at L3) memory ops for cross-block handoff ----
__device__ __forceinline__ void st_b16_sys(u16* a, unsigned v) {
  asm volatile("global_store_short %0, %1, off sc0 sc1" :: "v"(a), "v"(v) : "memory");
}
__device__ __forceinline__ void st_b32_sys(int* a, int v) {
  asm volatile("global_store_dword %0, %1, off sc0 sc1" :: "v"(a), "v"(v) : "memory");
}
__device__ __forceinline__ int ld_b32_sys(const int* a) {
  int v;
  asm volatile("global_load_dword %0, %1, off sc0 sc1\n\ts_waitcnt vmcnt(0)"
               : "=v"(v) : "v"(a) : "memory");
  return v;
}

// ---------------- generic bf16 MFMA GEMM: C = A @ B(^T) (+bias)(+tanh) ----------------
// A: [M,K] bf16 row-major (lda). BT: B=[N,K] (ldb over K). NN: B=[K,N] (ldb over N).
// Tiles: 64x64, BK=64, 256 threads (4 waves 2x2), M,N,K all multiples of 64.
template<bool BT, bool OBF, bool DOTANH, bool BIAS>
__global__ __launch_bounds__(256) void gemm_kernel(
    const u16* __restrict__ A, const u16* __restrict__ Bm, void* __restrict__ Cv,
    const float* __restrict__ bias,
    int K, int lda, int ldb, int ldc,
    long a_bs, long b_bs, long c_bs)
{
  __shared__ u16 As[64][72];
  __shared__ u16 Bs[64][72];
  const int tid = threadIdx.x;
  const long m0 = (long)blockIdx.y * 64, n0 = (long)blockIdx.x * 64;
  const int z = blockIdx.z;
  const u16* Ab = A + (long)z * a_bs;
  const u16* Bb = Bm + (long)z * b_bs;
  const int lane = tid & 63, w = tid >> 6;
  const int wm = w >> 1, wn = w & 1;
  f32x4 acc[2][2] = {};
  for (int k0 = 0; k0 < K; k0 += 64) {
#pragma unroll
    for (int i = 0; i < 2; i++) {
      int c = tid + 256 * i;
      int r = c >> 3, kk = (c & 7) << 3;
      *(short8*)&As[r][kk] = *(const short8*)&Ab[(m0 + r) * (long)lda + k0 + kk];
    }
    if (BT) {
#pragma unroll
      for (int i = 0; i < 2; i++) {
        int c = tid + 256 * i;
        int r = c >> 3, kk = (c & 7) << 3;
        *(short8*)&Bs[r][kk] = *(const short8*)&Bb[(n0 + r) * (long)ldb + k0 + kk];
      }
    } else {
#pragma unroll
      for (int i = 0; i < 2; i++) {
        int c = tid + 256 * i;
        int kk = c >> 3, nn = (c & 7) << 3;
        const u16* s = &Bb[(long)(k0 + kk) * ldb + n0 + nn];
#pragma unroll
        for (int j = 0; j < 8; j++) Bs[nn + j][kk] = s[j];
      }
    }
    __syncthreads();
#pragma unroll
    for (int kf = 0; kf < 2; kf++) {
      const int ko = kf * 32 + (lane >> 4) * 8;
      short8 a0 = *(const short8*)&As[wm * 32 + (lane & 15)][ko];
      short8 a1 = *(const short8*)&As[wm * 32 + 16 + (lane & 15)][ko];
      short8 b0 = *(const short8*)&Bs[wn * 32 + (lane & 15)][ko];
      short8 b1 = *(const short8*)&Bs[wn * 32 + 16 + (lane & 15)][ko];
      acc[0][0] = mfma16(a0, b0, acc[0][0]);
      acc[0][1] = mfma16(a0, b1, acc[0][1]);
      acc[1][0] = mfma16(a1, b0, acc[1][0]);
      acc[1][1] = mfma16(a1, b1, acc[1][1]);
    }
    __syncthreads();
  }
#pragma unroll
  for (int m = 0; m < 2; m++)
#pragma unroll
    for (int n = 0; n < 2; n++) {
#pragma unroll
      for (int r = 0; r < 4; r++) {
        long row = m0 + wm * 32 + m * 16 + (lane >> 4) * 4 + r;
        long col = n0 + wn * 32 + n * 16 + (lane & 15);
        float v = acc[m][n][r];
        if (BIAS) v += bias[col];
        if (DOTANH) v = tanhf(v);
        if (OBF) ((u16*)Cv)[(long)z * c_bs + row * ldc + col] = f2bf(v);
        else ((float*)Cv)[(long)z * c_bs + row * ldc + col] = v;
      }
    }
}

// ---------------- persistent LSTM: 32 blocks, L3 write-through handoff per step ----------------
// Gate-interleaved layout: permuted gate col n -> orig row (n&3)*512 + (n>>2).
// Block nb owns hidden units [nb*16, nb*16+16) = permuted cols [nb*64, nb*64+64).
// All cross-block data (Hbuf, flags) moves via sc0 sc1 (L1/L2-bypass, L3-coherent)
// loads/stores -> no buffer_wbl2 / buffer_inv anywhere in the loop.
// MODE 0: write h into cat[:, 512:1024] (bf16). MODE 1: write h into h2 (bf16, ld 512).
template<int MODE>
__global__ __launch_bounds__(256) void lstm_kernel(
    const float* __restrict__ xw,   // [4096][2048] permuted, biases folded in
    const u16* __restrict__ Whh,    // [2048][512] permuted rows, bf16
    u16* __restrict__ Hbuf,         // [2][16][512] bf16 ping-pong (pre-zeroed)
    u16* __restrict__ hout,
    int* __restrict__ flag)         // 32 ints, pre-zeroed
{
  const int nb = blockIdx.x;
  const int tid = threadIdx.x;
  const int lane = tid & 63, w = tid >> 6;
  const int ncol0 = nb * 64 + w * 16;
  short8 bfrag[16];
  {
    const u16* wr = Whh + (long)(ncol0 + (lane & 15)) * 512 + ((lane >> 4) * 8);
#pragma unroll
    for (int kf = 0; kf < 16; kf++) bfrag[kf] = *(const short8*)&wr[kf * 32];
  }
  const int b = tid >> 4, jl = tid & 15;
  const int jglob = nb * 16 + jl;
  float c = 0.f;
  __shared__ float gbuf[16][64];
  // prefetch step-0 gate pre-activations (xw is immutable -> stays in regs)
  float4 xg = *(const float4*)&xw[((long)b * LL) * GG + nb * 64 + jl * 4];
  const u16* arbase = Hbuf + (lane & 15) * 512 + ((lane >> 4) * 8);
  for (int t = 0; t < LL; t++) {
    // ---- load full h_{t-1} fragment set straight from L3 (sc0 sc1) ----
    const u16* ar = arbase + (t & 1) * (16 * 512);
    short8 af[16];
#pragma unroll
    for (int kf = 0; kf < 16; kf++)
      asm volatile("global_load_dwordx4 %0, %1, off sc0 sc1"
                   : "=v"(af[kf]) : "v"(ar + kf * 32));
    asm volatile("s_waitcnt vmcnt(0)" ::: "memory");
    __builtin_amdgcn_sched_barrier(0);   // rule #18: keep MFMAs after the waitcnt
    f32x4 acc0 = {}, acc1 = {};
#pragma unroll
    for (int kf = 0; kf < 8; kf++) {
      acc0 = mfma16(af[2 * kf], bfrag[2 * kf], acc0);
      acc1 = mfma16(af[2 * kf + 1], bfrag[2 * kf + 1], acc1);
    }
    f32x4 acc = acc0 + acc1;
#pragma unroll
    for (int r = 0; r < 4; r++)
      gbuf[(lane >> 4) * 4 + r][w * 16 + (lane & 15)] = acc[r];
    __syncthreads();
    float gi = sigmoidf_(gbuf[b][jl * 4 + 0] + xg.x);
    float gf = sigmoidf_(gbuf[b][jl * 4 + 1] + xg.y);
    float gg = tanhf(gbuf[b][jl * 4 + 2] + xg.z);
    float go = sigmoidf_(gbuf[b][jl * 4 + 3] + xg.w);
    c = gf * c + gi * gg;
    float h = go * tanhf(c);
    u16 hb = f2bf(h);
    // ---- publish h_t: write-through to L3, drain, block-barrier, post flag ----
    st_b16_sys(&Hbuf[((t + 1) & 1) * (16 * 512) + b * 512 + jglob], hb);
    asm volatile("s_waitcnt vmcnt(0)" ::: "memory");
    __syncthreads();
    if (tid == 0) st_b32_sys(&flag[nb], t + 1);
    // off the critical path: hout write (plain, dirty L2 until dispatch end)
    if (MODE == 0) hout[((long)b * LL + t) * 1024 + 512 + jglob] = hb;
    else           hout[((long)b * LL + t) * 512 + jglob] = hb;
    // prefetch next step's xw slice while flags propagate
    float4 xg_next = {};
    if (t + 1 < LL)
      xg_next = *(const float4*)&xw[((long)b * LL + (t + 1)) * GG + nb * 64 + jl * 4];
    // ---- spin: every lane watches one of the 32 flags (relaxed sc0 sc1 loads) ----
    if (t + 1 < LL) {
      const int target = t + 1;
      const int* fp = &flag[lane & 31];
      while (ld_b32_sys(fp) < target) {}
    }
    xg = xg_next;
  }
}

// ---------------- small kernels ----------------
__global__ void fc1_kernel(const float* __restrict__ x, const float* __restrict__ wgt,
                           const float* __restrict__ bias, float* __restrict__ feat) {
  __shared__ float xs[ENC];
  int bb = blockIdx.x, j = threadIdx.x;
  for (int k = j; k < ENC; k += 256) xs[k] = x[bb * ENC + k];
  __syncthreads();
  float s = bias[j];
  const float* wr = wgt + (long)j * ENC;
  for (int k = 0; k < ENC; k += 4) {
    float4 wv = *(const float4*)&wr[k];
    s += xs[k] * wv.x + xs[k + 1] * wv.y + xs[k + 2] * wv.z + xs[k + 3] * wv.w;
  }
  feat[bb * EMBD + j] = s;
}

__global__ void bn_embed0_kernel(const float* __restrict__ feat, const float* __restrict__ g,
                                 const float* __restrict__ bb, u16* __restrict__ seq) {
  int j = threadIdx.x;  // 256 features, 1 block
  float mu = 0.f, m2 = 0.f;
  for (int i = 0; i < BB; i++) { float v = feat[i * EMBD + j]; mu += v; m2 += v * v; }
  mu *= (1.f / BB);
  float var = m2 * (1.f / BB) - mu * mu;
  float sc = g[j] * rsqrtf(var + 1e-5f);
  float sh = bb[j];
  for (int i = 0; i < BB; i++) {
    float v = (feat[i * EMBD + j] - mu) * sc + sh;
    seq[((long)i * LL) * EMBD + j] = f2bf(v);
  }
}

__global__ void embed_kernel(const int* __restrict__ y, const float* __restrict__ emb,
                             u16* __restrict__ seq) {
  int t = blockIdx.x, bb = blockIdx.y;
  int tok = y[bb * TY + t];
  int j = threadIdx.x;
  seq[((long)bb * LL + 1 + t) * EMBD + j] = f2bf(emb[(long)tok * EMBD + j]);
}

__global__ __launch_bounds__(256) void softmax_kernel(const float* __restrict__ sc,
                                                      u16* __restrict__ wsm) {
  int row = blockIdx.x;
  int q = row & (LL - 1);
  int k = threadIdx.x;
  __shared__ float red[8];
  float v = (k <= q) ? sc[(long)row * LL + k] : -3.4e38f;
  float m = v;
#pragma unroll
  for (int o = 32; o > 0; o >>= 1) m = fmaxf(m, __shfl_xor(m, o));
  if ((k & 63) == 0) red[k >> 6] = m;
  __syncthreads();
  m = fmaxf(fmaxf(red[0], red[1]), fmaxf(red[2], red[3]));
  float e = (k <= q) ? expf(v - m) : 0.f;
  float s = e;
#pragma unroll
  for (int o = 32; o > 0; o >>= 1) s += __shfl_xor(s, o);
  if ((k & 63) == 0) red[4 + (k >> 6)] = s;
  __syncthreads();
  s = red[4] + red[5] + red[6] + red[7];
  wsm[(long)row * LL + k] = f2bf(e / s);
}

__global__ void conv_bf16_kernel(const float* __restrict__ s, u16* __restrict__ d) {
  long i = ((long)blockIdx.x * 256 + threadIdx.x) * 4;
  float4 v = *(const float4*)&s[i];
  u16x4 o = {f2bf(v.x), f2bf(v.y), f2bf(v.z), f2bf(v.w)};
  *(u16x4*)&d[i] = o;
}

__global__ void conv_lstm_w_kernel(const float* __restrict__ s, u16* __restrict__ d, int ldk) {
  int n = blockIdx.x;  // 0..2047 permuted
  int r = (n & 3) * DEC + (n >> 2);
  for (int k = threadIdx.x; k < ldk; k += 256)
    d[(long)n * ldk + k] = f2bf(s[(long)r * ldk + k]);
}

__global__ void conv_lstm_b_kernel(const float* __restrict__ bih, const float* __restrict__ bhh,
                                   float* __restrict__ d) {
  int n = blockIdx.x * 256 + threadIdx.x;
  int r = (n & 3) * DEC + (n >> 2);
  d[n] = bih[r] + bhh[r];
}

extern "C" void kernel_launch(void* const* d_in, const int* in_sizes, int n_in,
                              void* d_out, int out_size, void* d_ws, size_t ws_size,
                              hipStream_t stream) {
  const float* x      = (const float*)d_in[0];
  const int*   y      = (const int*)d_in[1];
  const float* fc1_w  = (const float*)d_in[2];
  const float* fc1_b  = (const float*)d_in[3];
  const float* bn_g   = (const float*)d_in[4];
  const float* bn_b   = (const float*)d_in[5];
  const float* emb    = (const float*)d_in[6];
  const float* l1_Wih = (const float*)d_in[7];
  const float* l1_Whh = (const float*)d_in[8];
  const float* l1_bih = (const float*)d_in[9];
  const float* l1_bhh = (const float*)d_in[10];
  const float* Wout   = (const float*)d_in[11];
  const float* dc_Wih = (const float*)d_in[12];
  const float* dc_Whh = (const float*)d_in[13];
  const float* dc_bih = (const float*)d_in[14];
  const float* dc_bhh = (const float*)d_in[15];
  const float* fc2_w  = (const float*)d_in[16];
  const float* fc2_b  = (const float*)d_in[17];
  float* out = (float*)d_out;

  char* ws = (char*)d_ws;
  float* xw     = (float*)(ws + 0);          // 4096*2048 f32 (reused for both LSTMs)
  u16*   seqb   = (u16*)(ws + 33554432);     // 4096*256 bf16
  u16*   cat    = (u16*)(ws + 35651584);     // 4096*1024 bf16  [mix | h1]
  float* scores = (float*)(ws + 44040192);   // 16*256*256 f32
  u16*   wsm    = (u16*)(ws + 48234496);     // 16*256*256 bf16
  u16*   attnb  = (u16*)(ws + 50331648);     // 4096*512 bf16
  u16*   h2b    = (u16*)(ws + 54525952);     // 4096*512 bf16
  u16*   wih1   = (u16*)(ws + 58720256);     // 2048*256
  u16*   whh1   = (u16*)(ws + 59768832);     // 2048*512
  u16*   wih2   = (u16*)(ws + 61865984);     // 2048*512
  u16*   whh2   = (u16*)(ws + 63963136);     // 2048*512
  u16*   woutb  = (u16*)(ws + 66060288);     // 512*1024
  u16*   fc2wb  = (u16*)(ws + 67108864);     // 32000*512
  float* b1p    = (float*)(ws + 99876864);   // 2048
  float* b2p    = (float*)(ws + 99885056);   // 2048
  float* feat   = (float*)(ws + 99893248);   // 16*256
  u16*   Hb     = (u16*)(ws + 99909632);     // 2 lstms * 2 pings * 16*512
  int*   flags  = (int*)(ws + 99975168);     // 2 * 256B

  hipMemsetAsync(ws + 99909632, 0, 65536 + 512, stream);

  conv_lstm_w_kernel<<<GG, 256, 0, stream>>>(l1_Wih, wih1, EMBD);
  conv_lstm_w_kernel<<<GG, 256, 0, stream>>>(l1_Whh, whh1, DEC);
  conv_lstm_w_kernel<<<GG, 256, 0, stream>>>(dc_Wih, wih2, DEC);
  conv_lstm_w_kernel<<<GG, 256, 0, stream>>>(dc_Whh, whh2, DEC);
  conv_lstm_b_kernel<<<GG / 256, 256, 0, stream>>>(l1_bih, l1_bhh, b1p);
  conv_lstm_b_kernel<<<GG / 256, 256, 0, stream>>>(dc_bih, dc_bhh, b2p);
  conv_bf16_kernel<<<(DEC * 2 * DEC) / 1024, 256, 0, stream>>>(Wout, woutb);
  conv_bf16_kernel<<<(VV * DEC) / 1024, 256, 0, stream>>>(fc2_w, fc2wb);

  fc1_kernel<<<BB, 256, 0, stream>>>(x, fc1_w, fc1_b, feat);
  bn_embed0_kernel<<<1, 256, 0, stream>>>(feat, bn_g, bn_b, seqb);
  embed_kernel<<<dim3(TY, BB), 256, 0, stream>>>(y, emb, seqb);

  // xw1 = seq @ l1_Wih^T + (bih+bhh)   M=4096 N=2048 K=256
  gemm_kernel<true, false, false, true><<<dim3(GG / 64, M4 / 64, 1), 256, 0, stream>>>(
      seqb, wih1, xw, b1p, EMBD, EMBD, EMBD, GG, 0, 0, 0);
  // LSTM1 -> h1 into cat[:,512:1024]
  lstm_kernel<0><<<32, 256, 0, stream>>>(xw, whh1, Hb, cat, flags);
  // scores[b] = h1 @ h1^T   (per batch)
  gemm_kernel<true, false, false, false><<<dim3(LL / 64, LL / 64, BB), 256, 0, stream>>>(
      cat + 512, cat + 512, scores, nullptr, DEC, 1024, 1024, LL,
      (long)LL * 1024, (long)LL * 1024, (long)LL * LL);
  softmax_kernel<<<M4, 256, 0, stream>>>(scores, wsm);
  // mix[b] = wsm @ h1 (NN) -> cat[:,0:512] bf16
  gemm_kernel<false, true, false, false><<<dim3(DEC / 64, LL / 64, BB), 256, 0, stream>>>(
      wsm, cat + 512, cat, nullptr, LL, LL, 1024, 1024,
      (long)LL * LL, (long)LL * 1024, (long)LL * 1024);
  // attn = tanh(cat @ Wout^T)   M=4096 N=512 K=1024
  gemm_kernel<true, true, true, false><<<dim3(DEC / 64, M4 / 64, 1), 256, 0, stream>>>(
      cat, woutb, attnb, nullptr, 1024, 1024, 1024, DEC, 0, 0, 0);
  // xw2 = attn @ dc_Wih^T + (bih+bhh)   M=4096 N=2048 K=512
  gemm_kernel<true, false, false, true><<<dim3(GG / 64, M4 / 64, 1), 256, 0, stream>>>(
      attnb, wih2, xw, b2p, DEC, DEC, DEC, GG, 0, 0, 0);
  // LSTM2 -> h2
  lstm_kernel<1><<<32, 256, 0, stream>>>(xw, whh2, Hb + 2 * 16 * 512, h2b, flags + 64);
  // out = h2 @ fc2_w^T + fc2_b   M=4096 N=32000 K=512
  gemm_kernel<true, false, false, true><<<dim3(VV / 64, M4 / 64, 1), 256, 0, stream>>>(
      h2b, fc2wb, out, fc2_b, DEC, DEC, DEC, VV, 0, 0, 0);
}

// Round 4
// 2498.987 us; speedup vs baseline: 1.7026x; 1.0322x over previous
//
#include <hip/hip_runtime.h>

#define BB 16
#define TY 255
#define ENC 512
#define EMBD 256
#define DEC 512
#define VV 32000
#define LL 256          // TY+1
#define M4 4096         // B*L
#define GG 2048         // 4*DEC

typedef unsigned short u16;
typedef __attribute__((ext_vector_type(8))) short short8;
typedef __attribute__((ext_vector_type(4))) float f32x4;
typedef __attribute__((ext_vector_type(4))) unsigned short u16x4;

__device__ __forceinline__ u16 f2bf(float f) {
  unsigned u = __float_as_uint(f);
  u += 0x7fff + ((u >> 16) & 1);
  return (u16)(u >> 16);
}
__device__ __forceinline__ float bf2f(u16 h) {
  return __uint_as_float((unsigned)h << 16);
}
__device__ __forceinline__ f32x4 mfma16(short8 a, short8 b, f32x4 c) {
  return __builtin_amdgcn_mfma_f32_16x16x32_bf16(a, b, c, 0, 0, 0);
}
__device__ __forceinline__ float sigmoidf_(float x) { return 1.f / (1.f + expf(-x)); }

// ---- DEVICE-scope (sc1: L1/L2 bypass, coherent at Infinity Cache) ops for handoff ----
// (sc0 sc1 is SYSTEM scope -> host-coherent path, ~HBM latency; do not use for intra-GPU)
__device__ __forceinline__ void st_b16_dev(u16* a, unsigned v) {
  asm volatile("global_store_short %0, %1, off sc1" :: "v"(a), "v"(v) : "memory");
}
__device__ __forceinline__ void st_b32_dev(int* a, int v) {
  asm volatile("global_store_dword %0, %1, off sc1" :: "v"(a), "v"(v) : "memory");
}
__device__ __forceinline__ int ld_b32_dev(const int* a) {
  int v;
  asm volatile("global_load_dword %0, %1, off sc1\n\ts_waitcnt vmcnt(0)"
               : "=v"(v) : "v"(a) : "memory");
  return v;
}

// ---------------- generic bf16 MFMA GEMM: C = A @ B(^T) (+bias)(+tanh) ----------------
// A: [M,K] bf16 row-major (lda). BT: B=[N,K] (ldb over K). NN: B=[K,N] (ldb over N).
// Tiles: 64x64, BK=64, 256 threads (4 waves 2x2), M,N,K all multiples of 64.
template<bool BT, bool OBF, bool DOTANH, bool BIAS>
__global__ __launch_bounds__(256) void gemm_kernel(
    const u16* __restrict__ A, const u16* __restrict__ Bm, void* __restrict__ Cv,
    const float* __restrict__ bias,
    int K, int lda, int ldb, int ldc,
    long a_bs, long b_bs, long c_bs)
{
  __shared__ u16 As[64][72];
  __shared__ u16 Bs[64][72];
  const int tid = threadIdx.x;
  const long m0 = (long)blockIdx.y * 64, n0 = (long)blockIdx.x * 64;
  const int z = blockIdx.z;
  const u16* Ab = A + (long)z * a_bs;
  const u16* Bb = Bm + (long)z * b_bs;
  const int lane = tid & 63, w = tid >> 6;
  const int wm = w >> 1, wn = w & 1;
  f32x4 acc[2][2] = {};
  for (int k0 = 0; k0 < K; k0 += 64) {
#pragma unroll
    for (int i = 0; i < 2; i++) {
      int c = tid + 256 * i;
      int r = c >> 3, kk = (c & 7) << 3;
      *(short8*)&As[r][kk] = *(const short8*)&Ab[(m0 + r) * (long)lda + k0 + kk];
    }
    if (BT) {
#pragma unroll
      for (int i = 0; i < 2; i++) {
        int c = tid + 256 * i;
        int r = c >> 3, kk = (c & 7) << 3;
        *(short8*)&Bs[r][kk] = *(const short8*)&Bb[(n0 + r) * (long)ldb + k0 + kk];
      }
    } else {
#pragma unroll
      for (int i = 0; i < 2; i++) {
        int c = tid + 256 * i;
        int kk = c >> 3, nn = (c & 7) << 3;
        const u16* s = &Bb[(long)(k0 + kk) * ldb + n0 + nn];
#pragma unroll
        for (int j = 0; j < 8; j++) Bs[nn + j][kk] = s[j];
      }
    }
    __syncthreads();
#pragma unroll
    for (int kf = 0; kf < 2; kf++) {
      const int ko = kf * 32 + (lane >> 4) * 8;
      short8 a0 = *(const short8*)&As[wm * 32 + (lane & 15)][ko];
      short8 a1 = *(const short8*)&As[wm * 32 + 16 + (lane & 15)][ko];
      short8 b0 = *(const short8*)&Bs[wn * 32 + (lane & 15)][ko];
      short8 b1 = *(const short8*)&Bs[wn * 32 + 16 + (lane & 15)][ko];
      acc[0][0] = mfma16(a0, b0, acc[0][0]);
      acc[0][1] = mfma16(a0, b1, acc[0][1]);
      acc[1][0] = mfma16(a1, b0, acc[1][0]);
      acc[1][1] = mfma16(a1, b1, acc[1][1]);
    }
    __syncthreads();
  }
#pragma unroll
  for (int m = 0; m < 2; m++)
#pragma unroll
    for (int n = 0; n < 2; n++) {
#pragma unroll
      for (int r = 0; r < 4; r++) {
        long row = m0 + wm * 32 + m * 16 + (lane >> 4) * 4 + r;
        long col = n0 + wn * 32 + n * 16 + (lane & 15);
        float v = acc[m][n][r];
        if (BIAS) v += bias[col];
        if (DOTANH) v = tanhf(v);
        if (OBF) ((u16*)Cv)[(long)z * c_bs + row * ldc + col] = f2bf(v);
        else ((float*)Cv)[(long)z * c_bs + row * ldc + col] = v;
      }
    }
}

// ---------------- persistent LSTM: 32 blocks, device-scope L3 handoff per step ----------------
// Gate-interleaved layout: permuted gate col n -> orig row (n&3)*512 + (n>>2).
// Block nb owns hidden units [nb*16, nb*16+16) = permuted cols [nb*64, nb*64+64).
// Cross-block data (Hbuf, flags) moves via sc1 (device scope, L3-coherent) ops.
// Flags padded to one per 64B line; only wave 0 polls (less L3 line contention).
// MODE 0: write h into cat[:, 512:1024] (bf16). MODE 1: write h into h2 (bf16, ld 512).
template<int MODE>
__global__ __launch_bounds__(256) void lstm_kernel(
    const float* __restrict__ xw,   // [4096][2048] permuted, biases folded in
    const u16* __restrict__ Whh,    // [2048][512] permuted rows, bf16
    u16* __restrict__ Hbuf,         // [2][16][512] bf16 ping-pong (pre-zeroed)
    u16* __restrict__ hout,
    int* __restrict__ flag)         // 32 flags at stride 16 dwords (64B), pre-zeroed
{
  const int nb = blockIdx.x;
  const int tid = threadIdx.x;
  const int lane = tid & 63, w = tid >> 6;
  const int ncol0 = nb * 64 + w * 16;
  short8 bfrag[16];
  {
    const u16* wr = Whh + (long)(ncol0 + (lane & 15)) * 512 + ((lane >> 4) * 8);
#pragma unroll
    for (int kf = 0; kf < 16; kf++) bfrag[kf] = *(const short8*)&wr[kf * 32];
  }
  const int b = tid >> 4, jl = tid & 15;
  const int jglob = nb * 16 + jl;
  float c = 0.f;
  __shared__ float gbuf[16][64];
  // step-0 gate pre-activations (xw is immutable -> stays in regs)
  float4 xg = *(const float4*)&xw[((long)b * LL) * GG + nb * 64 + jl * 4];
  const u16* arbase = Hbuf + (lane & 15) * 512 + ((lane >> 4) * 8);
  for (int t = 0; t < LL; t++) {
    // ---- load full h_{t-1} fragment set from L3 (sc1) ----
    const u16* ar = arbase + (t & 1) * (16 * 512);
    short8 af[16];
#pragma unroll
    for (int kf = 0; kf < 16; kf++)
      asm volatile("global_load_dwordx4 %0, %1, off sc1"
                   : "=v"(af[kf]) : "v"(ar + kf * 32));
    asm volatile("s_waitcnt vmcnt(0)" ::: "memory");
    __builtin_amdgcn_sched_barrier(0);   // rule #18: keep MFMAs after the waitcnt
    f32x4 acc0 = {}, acc1 = {};
#pragma unroll
    for (int kf = 0; kf < 8; kf++) {
      acc0 = mfma16(af[2 * kf], bfrag[2 * kf], acc0);
      acc1 = mfma16(af[2 * kf + 1], bfrag[2 * kf + 1], acc1);
    }
    f32x4 acc = acc0 + acc1;
#pragma unroll
    for (int r = 0; r < 4; r++)
      gbuf[(lane >> 4) * 4 + r][w * 16 + (lane & 15)] = acc[r];
    __syncthreads();
    float gi = sigmoidf_(gbuf[b][jl * 4 + 0] + xg.x);
    float gf = sigmoidf_(gbuf[b][jl * 4 + 1] + xg.y);
    float gg = tanhf(gbuf[b][jl * 4 + 2] + xg.z);
    float go = sigmoidf_(gbuf[b][jl * 4 + 3] + xg.w);
    c = gf * c + gi * gg;
    float h = go * tanhf(c);
    u16 hb = f2bf(h);
    // ---- publish h_t (write-through to L3); hout overlaps the drain ----
    st_b16_dev(&Hbuf[((t + 1) & 1) * (16 * 512) + b * 512 + jglob], hb);
    if (MODE == 0) hout[((long)b * LL + t) * 1024 + 512 + jglob] = hb;
    else           hout[((long)b * LL + t) * 512 + jglob] = hb;
    asm volatile("s_waitcnt vmcnt(0)" ::: "memory");
    __syncthreads();
    if (tid == 0) st_b32_dev(&flag[nb << 4], t + 1);
    // waves 1-3: prefetch next xw slice now (latency hides under wave-0 spin)
    float4 xg_next = {};
    if (t + 1 < LL && w != 0)
      xg_next = *(const float4*)&xw[((long)b * LL + (t + 1)) * GG + nb * 64 + jl * 4];
    // ---- wave 0 spins on the 32 padded flags; others wait at the barrier ----
    if (t + 1 < LL && w == 0 && lane < 32) {
      const int target = t + 1;
      const int* fp = &flag[lane << 4];
      while (ld_b32_dev(fp) < target) {}
    }
    __syncthreads();
    if (t + 1 < LL && w == 0)
      xg_next = *(const float4*)&xw[((long)b * LL + (t + 1)) * GG + nb * 64 + jl * 4];
    xg = xg_next;
  }
}

// ---------------- small kernels ----------------
__global__ void fc1_kernel(const float* __restrict__ x, const float* __restrict__ wgt,
                           const float* __restrict__ bias, float* __restrict__ feat) {
  __shared__ float xs[ENC];
  int bb = blockIdx.x, j = threadIdx.x;
  for (int k = j; k < ENC; k += 256) xs[k] = x[bb * ENC + k];
  __syncthreads();
  float s = bias[j];
  const float* wr = wgt + (long)j * ENC;
  for (int k = 0; k < ENC; k += 4) {
    float4 wv = *(const float4*)&wr[k];
    s += xs[k] * wv.x + xs[k + 1] * wv.y + xs[k + 2] * wv.z + xs[k + 3] * wv.w;
  }
  feat[bb * EMBD + j] = s;
}

__global__ void bn_embed0_kernel(const float* __restrict__ feat, const float* __restrict__ g,
                                 const float* __restrict__ bb, u16* __restrict__ seq) {
  int j = threadIdx.x;  // 256 features, 1 block
  float mu = 0.f, m2 = 0.f;
  for (int i = 0; i < BB; i++) { float v = feat[i * EMBD + j]; mu += v; m2 += v * v; }
  mu *= (1.f / BB);
  float var = m2 * (1.f / BB) - mu * mu;
  float sc = g[j] * rsqrtf(var + 1e-5f);
  float sh = bb[j];
  for (int i = 0; i < BB; i++) {
    float v = (feat[i * EMBD + j] - mu) * sc + sh;
    seq[((long)i * LL) * EMBD + j] = f2bf(v);
  }
}

__global__ void embed_kernel(const int* __restrict__ y, const float* __restrict__ emb,
                             u16* __restrict__ seq) {
  int t = blockIdx.x, bb = blockIdx.y;
  int tok = y[bb * TY + t];
  int j = threadIdx.x;
  seq[((long)bb * LL + 1 + t) * EMBD + j] = f2bf(emb[(long)tok * EMBD + j]);
}

__global__ __launch_bounds__(256) void softmax_kernel(const float* __restrict__ sc,
                                                      u16* __restrict__ wsm) {
  int row = blockIdx.x;
  int q = row & (LL - 1);
  int k = threadIdx.x;
  __shared__ float red[8];
  float v = (k <= q) ? sc[(long)row * LL + k] : -3.4e38f;
  float m = v;
#pragma unroll
  for (int o = 32; o > 0; o >>= 1) m = fmaxf(m, __shfl_xor(m, o));
  if ((k & 63) == 0) red[k >> 6] = m;
  __syncthreads();
  m = fmaxf(fmaxf(red[0], red[1]), fmaxf(red[2], red[3]));
  float e = (k <= q) ? expf(v - m) : 0.f;
  float s = e;
#pragma unroll
  for (int o = 32; o > 0; o >>= 1) s += __shfl_xor(s, o);
  if ((k & 63) == 0) red[4 + (k >> 6)] = s;
  __syncthreads();
  s = red[4] + red[5] + red[6] + red[7];
  wsm[(long)row * LL + k] = f2bf(e / s);
}

__global__ void conv_bf16_kernel(const float* __restrict__ s, u16* __restrict__ d) {
  long i = ((long)blockIdx.x * 256 + threadIdx.x) * 4;
  float4 v = *(const float4*)&s[i];
  u16x4 o = {f2bf(v.x), f2bf(v.y), f2bf(v.z), f2bf(v.w)};
  *(u16x4*)&d[i] = o;
}

__global__ void conv_lstm_w_kernel(const float* __restrict__ s, u16* __restrict__ d, int ldk) {
  int n = blockIdx.x;  // 0..2047 permuted
  int r = (n & 3) * DEC + (n >> 2);
  for (int k = threadIdx.x; k < ldk; k += 256)
    d[(long)n * ldk + k] = f2bf(s[(long)r * ldk + k]);
}

__global__ void conv_lstm_b_kernel(const float* __restrict__ bih, const float* __restrict__ bhh,
                                   float* __restrict__ d) {
  int n = blockIdx.x * 256 + threadIdx.x;
  int r = (n & 3) * DEC + (n >> 2);
  d[n] = bih[r] + bhh[r];
}

extern "C" void kernel_launch(void* const* d_in, const int* in_sizes, int n_in,
                              void* d_out, int out_size, void* d_ws, size_t ws_size,
                              hipStream_t stream) {
  const float* x      = (const float*)d_in[0];
  const int*   y      = (const int*)d_in[1];
  const float* fc1_w  = (const float*)d_in[2];
  const float* fc1_b  = (const float*)d_in[3];
  const float* bn_g   = (const float*)d_in[4];
  const float* bn_b   = (const float*)d_in[5];
  const float* emb    = (const float*)d_in[6];
  const float* l1_Wih = (const float*)d_in[7];
  const float* l1_Whh = (const float*)d_in[8];
  const float* l1_bih = (const float*)d_in[9];
  const float* l1_bhh = (const float*)d_in[10];
  const float* Wout   = (const float*)d_in[11];
  const float* dc_Wih = (const float*)d_in[12];
  const float* dc_Whh = (const float*)d_in[13];
  const float* dc_bih = (const float*)d_in[14];
  const float* dc_bhh = (const float*)d_in[15];
  const float* fc2_w  = (const float*)d_in[16];
  const float* fc2_b  = (const float*)d_in[17];
  float* out = (float*)d_out;

  char* ws = (char*)d_ws;
  float* xw     = (float*)(ws + 0);          // 4096*2048 f32 (reused for both LSTMs)
  u16*   seqb   = (u16*)(ws + 33554432);     // 4096*256 bf16
  u16*   cat    = (u16*)(ws + 35651584);     // 4096*1024 bf16  [mix | h1]
  float* scores = (float*)(ws + 44040192);   // 16*256*256 f32
  u16*   wsm    = (u16*)(ws + 48234496);     // 16*256*256 bf16
  u16*   attnb  = (u16*)(ws + 50331648);     // 4096*512 bf16
  u16*   h2b    = (u16*)(ws + 54525952);     // 4096*512 bf16
  u16*   wih1   = (u16*)(ws + 58720256);     // 2048*256
  u16*   whh1   = (u16*)(ws + 59768832);     // 2048*512
  u16*   wih2   = (u16*)(ws + 61865984);     // 2048*512
  u16*   whh2   = (u16*)(ws + 63963136);     // 2048*512
  u16*   woutb  = (u16*)(ws + 66060288);     // 512*1024
  u16*   fc2wb  = (u16*)(ws + 67108864);     // 32000*512
  float* b1p    = (float*)(ws + 99876864);   // 2048
  float* b2p    = (float*)(ws + 99885056);   // 2048
  float* feat   = (float*)(ws + 99893248);   // 16*256
  u16*   Hb     = (u16*)(ws + 99909632);     // 2 lstms * 2 pings * 16*512 (64KB)
  int*   flags  = (int*)(ws + 99975168);     // 2 * 32 flags * 64B stride (8KB)

  hipMemsetAsync(ws + 99909632, 0, 65536 + 8192, stream);

  conv_lstm_w_kernel<<<GG, 256, 0, stream>>>(l1_Wih, wih1, EMBD);
  conv_lstm_w_kernel<<<GG, 256, 0, stream>>>(l1_Whh, whh1, DEC);
  conv_lstm_w_kernel<<<GG, 256, 0, stream>>>(dc_Wih, wih2, DEC);
  conv_lstm_w_kernel<<<GG, 256, 0, stream>>>(dc_Whh, whh2, DEC);
  conv_lstm_b_kernel<<<GG / 256, 256, 0, stream>>>(l1_bih, l1_bhh, b1p);
  conv_lstm_b_kernel<<<GG / 256, 256, 0, stream>>>(dc_bih, dc_bhh, b2p);
  conv_bf16_kernel<<<(DEC * 2 * DEC) / 1024, 256, 0, stream>>>(Wout, woutb);
  conv_bf16_kernel<<<(VV * DEC) / 1024, 256, 0, stream>>>(fc2_w, fc2wb);

  fc1_kernel<<<BB, 256, 0, stream>>>(x, fc1_w, fc1_b, feat);
  bn_embed0_kernel<<<1, 256, 0, stream>>>(feat, bn_g, bn_b, seqb);
  embed_kernel<<<dim3(TY, BB), 256, 0, stream>>>(y, emb, seqb);

  // xw1 = seq @ l1_Wih^T + (bih+bhh)   M=4096 N=2048 K=256
  gemm_kernel<true, false, false, true><<<dim3(GG / 64, M4 / 64, 1), 256, 0, stream>>>(
      seqb, wih1, xw, b1p, EMBD, EMBD, EMBD, GG, 0, 0, 0);
  // LSTM1 -> h1 into cat[:,512:1024]
  lstm_kernel<0><<<32, 256, 0, stream>>>(xw, whh1, Hb, cat, flags);
  // scores[b] = h1 @ h1^T   (per batch)
  gemm_kernel<true, false, false, false><<<dim3(LL / 64, LL / 64, BB), 256, 0, stream>>>(
      cat + 512, cat + 512, scores, nullptr, DEC, 1024, 1024, LL,
      (long)LL * 1024, (long)LL * 1024, (long)LL * LL);
  softmax_kernel<<<M4, 256, 0, stream>>>(scores, wsm);
  // mix[b] = wsm @ h1 (NN) -> cat[:,0:512] bf16
  gemm_kernel<false, true, false, false><<<dim3(DEC / 64, LL / 64, BB), 256, 0, stream>>>(
      wsm, cat + 512, cat, nullptr, LL, LL, 1024, 1024,
      (long)LL * LL, (long)LL * 1024, (long)LL * 1024);
  // attn = tanh(cat @ Wout^T)   M=4096 N=512 K=1024
  gemm_kernel<true, true, true, false><<<dim3(DEC / 64, M4 / 64, 1), 256, 0, stream>>>(
      cat, woutb, attnb, nullptr, 1024, 1024, 1024, DEC, 0, 0, 0);
  // xw2 = attn @ dc_Wih^T + (bih+bhh)   M=4096 N=2048 K=512
  gemm_kernel<true, false, false, true><<<dim3(GG / 64, M4 / 64, 1), 256, 0, stream>>>(
      attnb, wih2, xw, b2p, DEC, DEC, DEC, GG, 0, 0, 0);
  // LSTM2 -> h2
  lstm_kernel<1><<<32, 256, 0, stream>>>(xw, whh2, Hb + 2 * 16 * 512, h2b, flags + 1024);
  // out = h2 @ fc2_w^T + fc2_b   M=4096 N=32000 K=512
  gemm_kernel<true, false, false, true><<<dim3(VV / 64, M4 / 64, 1), 256, 0, stream>>>(
      h2b, fc2wb, out, fc2_b, DEC, DEC, DEC, VV, 0, 0, 0);
}